// Round 10
// baseline (30.326 us; speedup 1.0000x reference)
//
#include <hip/hip_runtime.h>
#include <hip/hip_bf16.h>

#define LATENT 16
#define STATE  16
#define NPOS   (64 * 8192)
#define NTILES (NPOS / 16)        // 32768 tiles of 16 positions

typedef __attribute__((ext_vector_type(4))) float f32x4;
typedef __attribute__((ext_vector_type(8))) short bf16x8;  // 8 bf16 in 4 VGPRs

static __device__ __forceinline__ short f2bf(float f) {
    __hip_bfloat16 h = __float2bfloat16(f);
    return (short)__builtin_bit_cast(unsigned short, h);
}

// ---------------- prep: pack W into MFMA fragment order ----------------
// ws layout: [0..15] f32 bias (const-term row); then 4608 ushort Wpack.
// Wpack[(c*64 + lane)*8 + jj] = bf16 W'[k = c*32 + (lane>>4)*8 + jj][lane&15]
// Used as the MFMA **A** operand (A[row=state][k]); theta is B.
// K order: k<256: x_I * x_J, I=k>>4, J=k&15 (off-diag weights halved);
//          k=256..271: linear x[k-256]; k=272..287: sin(x[k-272]).
__global__ __launch_bounds__(256) void prep_pack(const float* __restrict__ coef,
                                                 const float* __restrict__ mask,
                                                 float* __restrict__ wsf) {
    int id = blockIdx.x * 256 + threadIdx.x;
    if (id < 16) wsf[id] = coef[id] * mask[id];   // bias: ref row 0 (const)
    if (id >= 4608) return;
    int jj  = id & 7;
    int col = (id >> 3) & 15;
    int g   = (id >> 7) & 3;
    int c   = id >> 9;                    // 0..8
    int k   = c * 32 + g * 8 + jj;        // 0..287
    float scale = 1.0f;
    int row;
    if (k < 256) {
        int I = k >> 4, J = k & 15;
        int im = I < J ? I : J, jm = I < J ? J : I;
        int q = im * 16 - im * (im - 1) / 2 + (jm - im);  // comb_w_r index
        row = 17 + q;
        if (I != J) scale = 0.5f;
    } else if (k < 272) {
        row = 1 + (k - 256);
    } else {
        row = 153 + (k - 272);
    }
    float w = coef[row * STATE + col] * mask[row * STATE + col] * scale;
    ((ushort*)(wsf + 16))[id] = (ushort)f2bf(w);
}

// ---------------- main: one tile per wave, wave-churn latency hiding ----
// 8192 blocks x 4 waves = 32768 waves, one 16-position tile each.
// x-loads issue FIRST (HBM long pole), bfrag loads (L2/L3) overlap them.
// Swapped-operand MFMA: D col = position, row = state -> one dwordx4 store.
// All register state NAMED SSA (rule #20).
__global__ __launch_bounds__(256, 4) void sindy_mfma(const float* __restrict__ x,
                                                     const float* __restrict__ wsf,
                                                     float* __restrict__ out) {
    const int lane  = threadIdx.x & 63;
    const int wid   = threadIdx.x >> 6;
    const int g     = lane >> 4;          // K-slice group 0..3
    const int col   = lane & 15;          // position-in-tile
    const bool hiJ  = (g & 1) != 0;       // J-half this lane multiplies
    const bool hiI  = (g >> 1) != 0;      // I parity this lane covers

    const int tile = blockIdx.x * 4 + wid;           // 0..32767
    const long base = (long)(tile * 16 + col) * 4;   // float4 idx of my row

    // x row loads first: these are the long-latency ops to get in flight
    const float4* x4 = (const float4*)x;
    const float4 A = x4[base + 0];
    const float4 B = x4[base + 1];
    const float4 C = x4[base + 2];
    const float4 D = x4[base + 3];

    // W fragments (A operand): L2/L3-resident, overlap the x loads
    const ushort* Wpack = (const ushort*)(wsf + 16);
    const bf16x8 b0 = *(const bf16x8*)(Wpack + (0 * 64 + lane) * 8);
    const bf16x8 b1 = *(const bf16x8*)(Wpack + (1 * 64 + lane) * 8);
    const bf16x8 b2 = *(const bf16x8*)(Wpack + (2 * 64 + lane) * 8);
    const bf16x8 b3 = *(const bf16x8*)(Wpack + (3 * 64 + lane) * 8);
    const bf16x8 b4 = *(const bf16x8*)(Wpack + (4 * 64 + lane) * 8);
    const bf16x8 b5 = *(const bf16x8*)(Wpack + (5 * 64 + lane) * 8);
    const bf16x8 b6 = *(const bf16x8*)(Wpack + (6 * 64 + lane) * 8);
    const bf16x8 b7 = *(const bf16x8*)(Wpack + (7 * 64 + lane) * 8);
    const bf16x8 b8 = *(const bf16x8*)(Wpack + (8 * 64 + lane) * 8);

    // bias per STATE: acc reg r holds state g*4+r
    const float4 bias4 = *(const float4*)(wsf + g * 4);

    // xv: the J-half this lane multiplies (value selects, not addresses)
    const float xv0 = hiJ ? C.x : A.x;
    const float xv1 = hiJ ? C.y : A.y;
    const float xv2 = hiJ ? C.z : A.z;
    const float xv3 = hiJ ? C.w : A.w;
    const float xv4 = hiJ ? D.x : B.x;
    const float xv5 = hiJ ? D.y : B.y;
    const float xv6 = hiJ ? D.z : B.z;
    const float xv7 = hiJ ? D.w : B.w;
    // xi: element 2c + hiI
    const float xi0 = hiI ? A.y : A.x;
    const float xi1 = hiI ? A.w : A.z;
    const float xi2 = hiI ? B.y : B.x;
    const float xi3 = hiI ? B.w : B.z;
    const float xi4 = hiI ? C.y : C.x;
    const float xi5 = hiI ? C.w : C.z;
    const float xi6 = hiI ? D.y : D.x;
    const float xi7 = hiI ? D.w : D.z;

    f32x4 acc = {bias4.x, bias4.y, bias4.z, bias4.w};

#define QUAD(BF, XI)                                                     \
    {                                                                    \
        bf16x8 af;                                                       \
        af[0] = f2bf((XI) * xv0); af[1] = f2bf((XI) * xv1);              \
        af[2] = f2bf((XI) * xv2); af[3] = f2bf((XI) * xv3);              \
        af[4] = f2bf((XI) * xv4); af[5] = f2bf((XI) * xv5);              \
        af[6] = f2bf((XI) * xv6); af[7] = f2bf((XI) * xv7);              \
        acc = __builtin_amdgcn_mfma_f32_16x16x32_bf16(BF, af, acc, 0, 0, 0); \
    }
    QUAD(b0, xi0) QUAD(b1, xi1) QUAD(b2, xi2) QUAD(b3, xi3)
    QUAD(b4, xi4) QUAD(b5, xi5) QUAD(b6, xi6) QUAD(b7, xi7)
#undef QUAD
    // chunk 8: g<2 -> linear xv; g>=2 -> sin(xv)
    {
        const bool us = (g >= 2);
        bf16x8 af;
        af[0] = f2bf(us ? __sinf(xv0) : xv0);
        af[1] = f2bf(us ? __sinf(xv1) : xv1);
        af[2] = f2bf(us ? __sinf(xv2) : xv2);
        af[3] = f2bf(us ? __sinf(xv3) : xv3);
        af[4] = f2bf(us ? __sinf(xv4) : xv4);
        af[5] = f2bf(us ? __sinf(xv5) : xv5);
        af[6] = f2bf(us ? __sinf(xv6) : xv6);
        af[7] = f2bf(us ? __sinf(xv7) : xv7);
        acc = __builtin_amdgcn_mfma_f32_16x16x32_bf16(b8, af, acc, 0, 0, 0);
    }

    // D^T: lane writes states g*4..g*4+3 of position col -> one dwordx4;
    // 64 lanes cover the tile's full 1 KB contiguously.
    float4 res;
    res.x = acc[0]; res.y = acc[1]; res.z = acc[2]; res.w = acc[3];
    *(float4*)(out + (long)(tile * 16 + col) * STATE + g * 4) = res;
}

extern "C" void kernel_launch(void* const* d_in, const int* in_sizes, int n_in,
                              void* d_out, int out_size, void* d_ws, size_t ws_size,
                              hipStream_t stream) {
    const float* x    = (const float*)d_in[0];
    const float* coef = (const float*)d_in[1];
    const float* mask = (const float*)d_in[2];
    float*       wsf  = (float*)d_ws;     // 16 f32 bias + 4608 ushort Wpack
    float*       out  = (float*)d_out;

    prep_pack<<<18, 256, 0, stream>>>(coef, mask, wsf);
    sindy_mfma<<<NTILES / 4, 256, 0, stream>>>(x, wsf, out);  // 8192 blocks
}